// Round 11
// baseline (320.641 us; speedup 1.0000x reference)
//
#include <hip/hip_runtime.h>

#define N_NODES 50000
#define N_EDGES 500000

typedef __attribute__((ext_vector_type(8))) short short8;
typedef __attribute__((ext_vector_type(8))) unsigned short ushort8v;
typedef __attribute__((ext_vector_type(4))) float floatx4;
typedef __attribute__((ext_vector_type(4))) unsigned int uint4v;

__device__ inline float bf2f(unsigned short u) {
    unsigned int x = ((unsigned int)u) << 16;
    return __builtin_bit_cast(float, x);
}
__device__ inline unsigned short f2bf(float f) {  // round-to-nearest-even
    unsigned int x = __builtin_bit_cast(unsigned int, f);
    x += 0x7fff + ((x >> 16) & 1);
    return (unsigned short)(x >> 16);
}

// async 16B global -> LDS; LDS dest must be wave-uniform base + lane*16
__device__ __forceinline__ void gld_lds16(const unsigned short* g, unsigned short* l) {
    __builtin_amdgcn_global_load_lds((const __attribute__((address_space(1))) void*)g,
                                     (__attribute__((address_space(3))) void*)l, 16, 0, 0);
}

// accumulate 8 bf16 (16B) into 4 float2 pairs: lo = u<<16, hi = u & 0xFFFF0000
__device__ inline void accum16B(float2* a, ushort8v rv) {
    uint4v u = __builtin_bit_cast(uint4v, rv);
    #pragma unroll
    for (int p = 0; p < 4; p++) {
        float lo = __builtin_bit_cast(float, u[p] << 16);
        float hi = __builtin_bit_cast(float, u[p] & 0xFFFF0000u);
        a[p].x += lo;
        a[p].y += hi;
    }
}

// ---------------- merged hist + prep + zero(bsum,out) ----------------

__global__ __launch_bounds__(256) void histprep_kernel(const int* __restrict__ dst,
                                                       int* __restrict__ deg,
                                                       const float* __restrict__ W1,
                                                       const float* __restrict__ W2,
                                                       const float* __restrict__ W3,
                                                       const float* __restrict__ x,
                                                       unsigned short* __restrict__ Wt1,
                                                       unsigned short* __restrict__ Wt2,
                                                       unsigned short* __restrict__ Wt3,
                                                       unsigned short* __restrict__ xb,
                                                       int* __restrict__ bsum,
                                                       float* __restrict__ outZ) {
    int idx = blockIdx.x * 256 + threadIdx.x;
    if (idx < N_EDGES) { atomicAdd(&deg[dst[idx]], 1); return; }
    idx -= N_EDGES;
    if (idx < 32768) {
        if (idx < 256) bsum[idx] = 0;       // zero scan publication slots
        if (idx < 128) outZ[idx] = 0.f;     // zero final output (poisoned each call)
        int k = idx >> 8, n = idx & 255;
        Wt1[n * 128 + k] = f2bf(W1[idx]);
    } else if (idx < 98304) {
        int i = idx - 32768;
        int k = i >> 8, n = i & 255;
        Wt2[n * 256 + k] = f2bf(W2[i]);
    } else if (idx < 131072) {
        int i = idx - 98304;
        int k = i >> 7, n = i & 127;
        Wt3[n * 256 + k] = f2bf(W3[i]);
    } else {
        int i = (idx - 131072) * 4;
        if (i < N_NODES * 128) {
            float4 v = *(const float4*)(x + i);
            ushort4 o;
            o.x = f2bf(v.x); o.y = f2bf(v.y); o.z = f2bf(v.z); o.w = f2bf(v.w);
            *(ushort4*)(xb + i) = o;
        }
    }
}

// ---------------- single-pass scan + finalize ----------------

__global__ __launch_bounds__(256) void scan_onepass_kernel(int* __restrict__ cur,
                                                           int* __restrict__ bsum,
                                                           int* __restrict__ off, int n) {
    __shared__ int s[256];
    int b = blockIdx.x, t = threadIdx.x;
    int i = b * 256 + t;
    int v = (i < n) ? cur[i] : 0;
    s[t] = v;
    __syncthreads();
    #pragma unroll
    for (int d = 1; d < 256; d <<= 1) {
        int u = (t >= d) ? s[t - d] : 0;
        __syncthreads();
        s[t] += u;
        __syncthreads();
    }
    int incl = s[t];
    if (t == 255) atomicExch(&bsum[b], s[255] + 1);   // publish (value+1, nonzero flag)
    int pre = 0;
    if (t < b) {
        volatile int* p = (volatile int*)&bsum[t];
        int vv;
        while ((vv = *p) == 0) { }
        pre = vv - 1;
    }
    __syncthreads();
    s[t] = pre;
    __syncthreads();
    #pragma unroll
    for (int d = 128; d > 0; d >>= 1) {
        if (t < d) s[t] += s[t + d];
        __syncthreads();
    }
    int base = s[0];
    if (i == 0) off[0] = 0;
    if (i < n) {
        int inclG = base + incl;
        off[i + 1] = inclG;
        cur[i] = inclG - v;   // cur held deg; now row start
    }
}

__global__ void fill_kernel(const int* __restrict__ src, const int* __restrict__ dst,
                            int* __restrict__ cur, int* __restrict__ csr, int nE) {
    int e = blockIdx.x * 256 + threadIdx.x;
    if (e < nE) {
        int p = atomicAdd(&cur[dst[e]], 1);
        csr[p] = src[e];
    }
}

// ---------------- fused agg + GEMM: gather 64 A-rows into LDS, then MFMA ------------
// Block: 512 thr (8 waves), BM=64, BN=256 (=N). A gathered once into padded LDS.
// B is NOT staged in LDS: W is 64-128 KB, L2-resident, shared by all 782 blocks —
// fragments are read straight from global in the K-loop. This keeps LDS at
// 17.4/33.8 KB (4 blocks/CU, wave-limited), removes all K-loop __syncthreads,
// and eliminates the 8-way Bs bank conflicts seen in round 10 (1.2M/dispatch).

template<int F>
__global__ __launch_bounds__(512) void fused_agg_gemm_kernel(const unsigned short* __restrict__ H,
                                                             const int* __restrict__ off,
                                                             const int* __restrict__ csr,
                                                             const unsigned short* __restrict__ Bt,
                                                             const float* __restrict__ bias,
                                                             unsigned short* __restrict__ C,
                                                             int M) {
    constexpr int BM = 64, BN = 256, BK = 32, KS = F / BK;
    constexpr int LDAF = F + 8;               // pad 8 shorts: 2-way bank aliasing = free
    constexpr int LPR = F / 8;                // lanes per gathered row (16B/lane)
    constexpr int G = 512 / LPR;              // concurrent gather groups
    __shared__ unsigned short Afull[BM * LDAF];
    int tid = threadIdx.x;
    int m0 = blockIdx.x * BM;

    // gather + aggregate rows m0..m0+63 into Afull
    {
        int gid = tid / LPR, li = tid % LPR;
        int f0 = li * 8;
        for (int n = gid; n < BM; n += G) {
            int node = m0 + n;
            if (node < M) {
                int s = off[node], e = off[node + 1];
                float2 a[4];
                #pragma unroll
                for (int p = 0; p < 4; p++) a[p] = make_float2(0.f, 0.f);
                int i = s;
                for (; i + 4 <= e; i += 4) {
                    int i0 = csr[i], i1 = csr[i + 1], i2 = csr[i + 2], i3 = csr[i + 3];
                    ushort8v r0 = *(const ushort8v*)(H + (size_t)i0 * F + f0);
                    ushort8v r1 = *(const ushort8v*)(H + (size_t)i1 * F + f0);
                    ushort8v r2 = *(const ushort8v*)(H + (size_t)i2 * F + f0);
                    ushort8v r3 = *(const ushort8v*)(H + (size_t)i3 * F + f0);
                    accum16B(a, r0); accum16B(a, r1); accum16B(a, r2); accum16B(a, r3);
                }
                for (; i < e; i++) {
                    ushort8v r0 = *(const ushort8v*)(H + (size_t)csr[i] * F + f0);
                    accum16B(a, r0);
                }
                ushort8v o;
                #pragma unroll
                for (int p = 0; p < 4; p++) { o[2 * p] = f2bf(a[p].x); o[2 * p + 1] = f2bf(a[p].y); }
                *(ushort8v*)&Afull[n * LDAF + f0] = o;
            }
        }
    }
    __syncthreads();   // only barrier in the kernel

    int wave = tid >> 6, lane = tid & 63;
    int wm = wave & 1, wn = wave >> 1;        // rows [wm*32,+32), cols [wn*64,+64)
    int mlane = lane & 15, kgrp = lane >> 4;
    floatx4 acc[2][4];
    #pragma unroll
    for (int i = 0; i < 2; i++)
        #pragma unroll
        for (int j = 0; j < 4; j++) acc[i][j] = (floatx4){0.f, 0.f, 0.f, 0.f};

    const unsigned short* bBase = Bt + (size_t)(wn * 64 + mlane) * F + kgrp * 8;

    #pragma unroll 2
    for (int ks = 0; ks < KS; ks++) {
        short8 af[2], bfr[4];
        #pragma unroll
        for (int nt = 0; nt < 4; nt++)        // B from global (L2-resident weights)
            bfr[nt] = *(const short8*)(bBase + (size_t)nt * 16 * F + ks * BK);
        #pragma unroll
        for (int mt = 0; mt < 2; mt++)
            af[mt] = *(const short8*)&Afull[(wm * 32 + mt * 16 + mlane) * LDAF + ks * BK + kgrp * 8];
        #pragma unroll
        for (int mt = 0; mt < 2; mt++)
            #pragma unroll
            for (int nt = 0; nt < 4; nt++)
                acc[mt][nt] = __builtin_amdgcn_mfma_f32_16x16x32_bf16(af[mt], bfr[nt],
                                                                      acc[mt][nt], 0, 0, 0);
    }
    #pragma unroll
    for (int mt = 0; mt < 2; mt++) {
        #pragma unroll
        for (int nt = 0; nt < 4; nt++) {
            int col = wn * 64 + nt * 16 + mlane;
            float bv = bias[col];
            #pragma unroll
            for (int r = 0; r < 4; r++) {
                int row = m0 + wm * 32 + mt * 16 + kgrp * 4 + r;
                if (row < M) {
                    float v = fmaxf(acc[mt][nt][r] + bv, 0.f);
                    C[(size_t)row * BN + col] = f2bf(v);
                }
            }
        }
    }
}

// ---------------- Aggregation F=128 body (used by agg3_mean) ------------------------

__device__ inline void agg128_body(const unsigned short* __restrict__ h,
                                   const int* __restrict__ off,
                                   const int* __restrict__ csr,
                                   int node, int quad, int f0, float2* a) {
    int s = __builtin_amdgcn_readfirstlane(off[node]);
    int e = __builtin_amdgcn_readfirstlane(off[node + 1]);
    int i = s;
    for (; i + 8 <= e; i += 8) {
        ushort8v r[2];
        #pragma unroll
        for (int j = 0; j < 2; j++) {
            int base = i + 4 * j;
            int i0 = csr[base], i1 = csr[base + 1], i2 = csr[base + 2], i3 = csr[base + 3];
            int id = quad == 0 ? i0 : quad == 1 ? i1 : quad == 2 ? i2 : i3;
            r[j] = *(const ushort8v*)(h + (size_t)id * 128 + f0);
        }
        #pragma unroll
        for (int j = 0; j < 2; j++) accum16B(a, r[j]);
    }
    int rem = e - i;
    if (rem > 0) {
        int nr = (rem + 3) >> 2;
        ushort8v r[2];
        #pragma unroll
        for (int j = 0; j < 2; j++) {
            if (j < nr) {
                int base = i + 4 * j;
                int c1 = base + 1 < e ? base + 1 : e - 1;
                int c2 = base + 2 < e ? base + 2 : e - 1;
                int c3 = base + 3 < e ? base + 3 : e - 1;
                int i0 = csr[base], i1 = csr[c1], i2 = csr[c2], i3 = csr[c3];
                int id = quad == 0 ? i0 : quad == 1 ? i1 : quad == 2 ? i2 : i3;
                r[j] = *(const ushort8v*)(h + (size_t)id * 128 + f0);
            }
        }
        #pragma unroll
        for (int j = 0; j < 2; j++) {
            if (j < nr && (i + 4 * j + quad) < e) accum16B(a, r[j]);
        }
    }
    #pragma unroll
    for (int p = 0; p < 4; p++) {
        a[p].x += __shfl_xor(a[p].x, 16, 64);
        a[p].y += __shfl_xor(a[p].y, 16, 64);
        a[p].x += __shfl_xor(a[p].x, 32, 64);
        a[p].y += __shfl_xor(a[p].y, 32, 64);
    }
}

// ---------------- layer-3: quad-split agg + bias + relu + block partial mean -------

__global__ __launch_bounds__(256) void agg3_mean_kernel(const unsigned short* __restrict__ t,
                                                        const int* __restrict__ off,
                                                        const int* __restrict__ csr,
                                                        const float* __restrict__ b3,
                                                        float* __restrict__ partial) {
    __shared__ float sm[4 * 128];
    int wave = threadIdx.x >> 6, lane = threadIdx.x & 63;
    int node = blockIdx.x * 4 + wave;
    int quad = lane >> 4;
    int f0 = (lane & 15) * 8;
    float2 a[4];
    #pragma unroll
    for (int p = 0; p < 4; p++) a[p] = make_float2(0.f, 0.f);
    agg128_body(t, off, csr, node, quad, f0, a);
    if (quad == 0) {
        #pragma unroll
        for (int p = 0; p < 4; p++) {
            sm[wave * 128 + f0 + 2 * p]     = fmaxf(a[p].x + b3[f0 + 2 * p], 0.f);
            sm[wave * 128 + f0 + 2 * p + 1] = fmaxf(a[p].y + b3[f0 + 2 * p + 1], 0.f);
        }
    }
    __syncthreads();
    if (threadIdx.x < 128) {
        int f = threadIdx.x;
        float p = sm[f] + sm[128 + f] + sm[256 + f] + sm[384 + f];
        partial[(size_t)blockIdx.x * 128 + f] = p;
    }
}

__global__ __launch_bounds__(256) void mean_reduce_kernel(const float* __restrict__ partial,
                                                          float* __restrict__ outp, int nRows) {
    __shared__ float s[256];
    int f = threadIdx.x & 127, half = threadIdx.x >> 7;
    int chunk = (nRows + gridDim.x - 1) / gridDim.x;
    int r0 = blockIdx.x * chunk;
    int r1 = r0 + chunk < nRows ? r0 + chunk : nRows;
    float acc = 0.f;
    for (int r = r0 + half; r < r1; r += 2) acc += partial[(size_t)r * 128 + f];
    s[threadIdx.x] = acc;
    __syncthreads();
    if (half == 0) atomicAdd(&outp[f], (s[f] + s[f + 128]) * (1.0f / N_NODES));
}

// ---------------- bf16 MFMA GEMM (gemm3 only): BM=64 x BN=128, 256 thr -------------

template<typename T> __device__ inline void storeC(T* p, float v);
template<> __device__ inline void storeC<float>(float* p, float v) { *p = v; }
template<> __device__ inline void storeC<unsigned short>(unsigned short* p, float v) { *p = f2bf(v); }

template<typename OUT_T>
__global__ __launch_bounds__(256) void gemm_bf16_kernel(const unsigned short* __restrict__ A,
                                                        const unsigned short* __restrict__ Bt,
                                                        const float* __restrict__ bias,
                                                        OUT_T* __restrict__ C,
                                                        int M, int K, int N, int doRelu) {
    constexpr int BM = 64, BN = 128, BK = 32;
    __shared__ unsigned short As[BM * BK];
    __shared__ unsigned short Bs[BN * BK];
    int tid = threadIdx.x;
    int m0 = blockIdx.y * BM, n0 = blockIdx.x * BN;
    int wave = tid >> 6, lane = tid & 63;
    int wm = wave >> 1, wn = wave & 1;
    int mlane = lane & 15, kgrp = lane >> 4;

    floatx4 acc[2][4];
    #pragma unroll
    for (int i = 0; i < 2; i++)
        #pragma unroll
        for (int j = 0; j < 4; j++) acc[i][j] = (floatx4){0.f, 0.f, 0.f, 0.f};

    for (int k0 = 0; k0 < K; k0 += BK) {
        {
            int c = tid;
            int r = c >> 2, cb = (c & 3) * 8;
            gld_lds16(A + (size_t)(m0 + r) * K + k0 + cb, &As[c * 8]);
        }
        #pragma unroll
        for (int it = 0; it < 2; it++) {
            int c = tid + it * 256;
            int r = c >> 2, cb = (c & 3) * 8;
            gld_lds16(Bt + (size_t)(n0 + r) * K + k0 + cb, &Bs[c * 8]);
        }
        __syncthreads();
        short8 af[2], bfr[4];
        #pragma unroll
        for (int mt = 0; mt < 2; mt++)
            af[mt] = *(const short8*)&As[(wm * 32 + mt * 16 + mlane) * BK + kgrp * 8];
        #pragma unroll
        for (int nt = 0; nt < 4; nt++)
            bfr[nt] = *(const short8*)&Bs[(wn * 64 + nt * 16 + mlane) * BK + kgrp * 8];
        #pragma unroll
        for (int mt = 0; mt < 2; mt++)
            #pragma unroll
            for (int nt = 0; nt < 4; nt++)
                acc[mt][nt] = __builtin_amdgcn_mfma_f32_16x16x32_bf16(af[mt], bfr[nt],
                                                                      acc[mt][nt], 0, 0, 0);
        __syncthreads();
    }
    #pragma unroll
    for (int mt = 0; mt < 2; mt++) {
        #pragma unroll
        for (int nt = 0; nt < 4; nt++) {
            int col = n0 + wn * 64 + nt * 16 + mlane;
            float bv = bias ? bias[col] : 0.f;
            #pragma unroll
            for (int r = 0; r < 4; r++) {
                int row = m0 + wm * 32 + mt * 16 + kgrp * 4 + r;
                if (row < M) {
                    float v = acc[mt][nt][r] + bv;
                    if (doRelu) v = fmaxf(v, 0.f);
                    storeC(C + (size_t)row * N + col, v);
                }
            }
        }
    }
}

// ---------------- launch ----------------

extern "C" void kernel_launch(void* const* d_in, const int* in_sizes, int n_in,
                              void* d_out, int out_size, void* d_ws, size_t ws_size,
                              hipStream_t stream) {
    const float* x   = (const float*)d_in[0];
    const int*   src = (const int*)d_in[1];
    const int*   dst = (const int*)d_in[2];
    const float* W1 = (const float*)d_in[3];
    const float* b1 = (const float*)d_in[4];
    const float* W2 = (const float*)d_in[5];
    const float* b2 = (const float*)d_in[6];
    const float* W3 = (const float*)d_in[7];
    const float* b3 = (const float*)d_in[8];
    float* out = (float*)d_out;

    char* ws = (char*)d_ws;
    size_t o = 0;
    auto alloc = [&](size_t bytes) -> char* {
        char* p = ws + o;
        o = (o + bytes + 255) & ~(size_t)255;
        return p;
    };
    int* off     = (int*)alloc((size_t)(N_NODES + 1) * 4);
    int* cur     = (int*)alloc((size_t)N_NODES * 4);
    int* csrIdx  = (int*)alloc((size_t)N_EDGES * 4);
    int* bsum    = (int*)alloc(256 * 4);
    unsigned short* Wt1 = (unsigned short*)alloc((size_t)128 * 256 * 2);
    unsigned short* Wt2 = (unsigned short*)alloc((size_t)256 * 256 * 2);
    unsigned short* Wt3 = (unsigned short*)alloc((size_t)256 * 128 * 2);
    char* R1 = alloc((size_t)N_NODES * 256 * 2);
    char* R2 = alloc((size_t)N_NODES * 256 * 2);
    char* R3 = alloc((size_t)N_NODES * 256 * 2);
    (void)alloc(65536);   // guard region for gemm3 tail-block over-reads past R3

    unsigned short* xb    = (unsigned short*)R1;  // 50000x128 bf16
    unsigned short* h1    = (unsigned short*)R3;  // 50000x256 bf16
    unsigned short* h2    = (unsigned short*)R2;  // 50000x256 bf16
    unsigned short* t     = (unsigned short*)R3;  // 50000x128 bf16 (h1 dead by then)
    float*          pmean = (float*)R1;           // 12500x128 fp32 (xb dead by then)

    const int nb = (N_NODES + 255) / 256;  // 196

    hipMemsetAsync(cur, 0, (size_t)N_NODES * 4, stream);
    const int hpThreads = N_EDGES + 131072 + N_NODES * 128 / 4;
    histprep_kernel<<<(hpThreads + 255) / 256, 256, 0, stream>>>(dst, cur, W1, W2, W3, x,
                                                                 Wt1, Wt2, Wt3, xb, bsum, out);
    scan_onepass_kernel<<<nb, 256, 0, stream>>>(cur, bsum, off, N_NODES);
    fill_kernel<<<(N_EDGES + 255) / 256, 256, 0, stream>>>(src, dst, cur, csrIdx, N_EDGES);

    const int mbF = (N_NODES + 63) / 64;  // 782

    // Layer 1 fused: h1 = relu(agg(xb) @ W1 + b1)
    fused_agg_gemm_kernel<128><<<mbF, 512, 0, stream>>>(xb, off, csrIdx, Wt1, b1, h1, N_NODES);
    // Layer 2 fused: h2 = relu(agg(h1) @ W2 + b2)
    fused_agg_gemm_kernel<256><<<mbF, 512, 0, stream>>>(h1, off, csrIdx, Wt2, b2, h2, N_NODES);
    // Layer 3 reordered: t = h2 @ W3 (bf16), then fused agg+bias+relu+partial-mean
    gemm_bf16_kernel<unsigned short><<<dim3(1, mbF), 256, 0, stream>>>(h2, Wt3, nullptr, t,
                                                                       N_NODES, 256, 128, 0);
    agg3_mean_kernel<<<N_NODES / 4, 256, 0, stream>>>(t, off, csrIdx, b3, pmean);
    mean_reduce_kernel<<<128, 256, 0, stream>>>(pmean, out, N_NODES / 4);
}

// Round 12
// 295.954 us; speedup vs baseline: 1.0834x; 1.0834x over previous
//
#include <hip/hip_runtime.h>

#define N_NODES 50000
#define N_EDGES 500000

typedef __attribute__((ext_vector_type(8))) short short8;
typedef __attribute__((ext_vector_type(8))) unsigned short ushort8v;
typedef __attribute__((ext_vector_type(4))) float floatx4;
typedef __attribute__((ext_vector_type(4))) unsigned int uint4v;

__device__ inline float bf2f(unsigned short u) {
    unsigned int x = ((unsigned int)u) << 16;
    return __builtin_bit_cast(float, x);
}
__device__ inline unsigned short f2bf(float f) {  // round-to-nearest-even
    unsigned int x = __builtin_bit_cast(unsigned int, f);
    x += 0x7fff + ((x >> 16) & 1);
    return (unsigned short)(x >> 16);
}

// async 16B global -> LDS; LDS dest must be wave-uniform base + lane*16
__device__ __forceinline__ void gld_lds16(const unsigned short* g, unsigned short* l) {
    __builtin_amdgcn_global_load_lds((const __attribute__((address_space(1))) void*)g,
                                     (__attribute__((address_space(3))) void*)l, 16, 0, 0);
}

// accumulate 8 bf16 (16B) into 4 float2 pairs: lo = u<<16, hi = u & 0xFFFF0000
__device__ inline void accum16B(float2* a, ushort8v rv) {
    uint4v u = __builtin_bit_cast(uint4v, rv);
    #pragma unroll
    for (int p = 0; p < 4; p++) {
        float lo = __builtin_bit_cast(float, u[p] << 16);
        float hi = __builtin_bit_cast(float, u[p] & 0xFFFF0000u);
        a[p].x += lo;
        a[p].y += hi;
    }
}

// ---------------- merged hist + prep + zero(bsum,out) ----------------

__global__ __launch_bounds__(256) void histprep_kernel(const int* __restrict__ dst,
                                                       int* __restrict__ deg,
                                                       const float* __restrict__ W1,
                                                       const float* __restrict__ W2,
                                                       const float* __restrict__ W3,
                                                       const float* __restrict__ x,
                                                       unsigned short* __restrict__ Wt1,
                                                       unsigned short* __restrict__ Wt2,
                                                       unsigned short* __restrict__ Wt3,
                                                       unsigned short* __restrict__ xb,
                                                       int* __restrict__ bsum,
                                                       float* __restrict__ outZ) {
    int idx = blockIdx.x * 256 + threadIdx.x;
    if (idx < N_EDGES) { atomicAdd(&deg[dst[idx]], 1); return; }
    idx -= N_EDGES;
    if (idx < 32768) {
        if (idx < 256) bsum[idx] = 0;       // zero scan publication slots
        if (idx < 128) outZ[idx] = 0.f;     // zero final output (poisoned each call)
        int k = idx >> 8, n = idx & 255;
        Wt1[n * 128 + k] = f2bf(W1[idx]);
    } else if (idx < 98304) {
        int i = idx - 32768;
        int k = i >> 8, n = i & 255;
        Wt2[n * 256 + k] = f2bf(W2[i]);
    } else if (idx < 131072) {
        int i = idx - 98304;
        int k = i >> 7, n = i & 127;
        Wt3[n * 256 + k] = f2bf(W3[i]);
    } else {
        int i = (idx - 131072) * 4;
        if (i < N_NODES * 128) {
            float4 v = *(const float4*)(x + i);
            ushort4 o;
            o.x = f2bf(v.x); o.y = f2bf(v.y); o.z = f2bf(v.z); o.w = f2bf(v.w);
            *(ushort4*)(xb + i) = o;
        }
    }
}

// ---------------- single-pass scan + finalize ----------------

__global__ __launch_bounds__(256) void scan_onepass_kernel(int* __restrict__ cur,
                                                           int* __restrict__ bsum,
                                                           int* __restrict__ off, int n) {
    __shared__ int s[256];
    int b = blockIdx.x, t = threadIdx.x;
    int i = b * 256 + t;
    int v = (i < n) ? cur[i] : 0;
    s[t] = v;
    __syncthreads();
    #pragma unroll
    for (int d = 1; d < 256; d <<= 1) {
        int u = (t >= d) ? s[t - d] : 0;
        __syncthreads();
        s[t] += u;
        __syncthreads();
    }
    int incl = s[t];
    if (t == 255) atomicExch(&bsum[b], s[255] + 1);   // publish (value+1, nonzero flag)
    int pre = 0;
    if (t < b) {
        volatile int* p = (volatile int*)&bsum[t];
        int vv;
        while ((vv = *p) == 0) { }
        pre = vv - 1;
    }
    __syncthreads();
    s[t] = pre;
    __syncthreads();
    #pragma unroll
    for (int d = 128; d > 0; d >>= 1) {
        if (t < d) s[t] += s[t + d];
        __syncthreads();
    }
    int base = s[0];
    if (i == 0) off[0] = 0;
    if (i < n) {
        int inclG = base + incl;
        off[i + 1] = inclG;
        cur[i] = inclG - v;   // cur held deg; now row start
    }
}

__global__ void fill_kernel(const int* __restrict__ src, const int* __restrict__ dst,
                            int* __restrict__ cur, int* __restrict__ csr, int nE) {
    int e = blockIdx.x * 256 + threadIdx.x;
    if (e < nE) {
        int p = atomicAdd(&cur[dst[e]], 1);
        csr[p] = src[e];
    }
}

// ---------------- fused agg + GEMM (v3) --------------------------------------------
// Block: 512 thr (8 waves), BM=64, BN=256 (=N). A gathered once into padded LDS.
// B: SINGLE 16 KB LDS buffer, XOR-swizzled chunk layout — staging via async
// global_load_lds stays chunk-linear (wave-uniform-base constraint), fragment
// reads are 2-way bank-aliased (free). LDS total 50.2/33.8 KB -> 3 blocks/CU
// x 8 waves = 24 waves/CU (grid 782 ~ 3.05/CU), +50% vs r10/r11 for the
// latency-bound gather. K-loop pipeline: read B frags -> barrier -> async-stage
// next k-step into the freed buffer -> MFMA (overlaps DMA) -> barrier.
// Swizzle: chunk j of row r stored at slot (j + (r>>1)) & 3.

template<int F>
__global__ __launch_bounds__(512) void fused_agg_gemm_kernel(const unsigned short* __restrict__ H,
                                                             const int* __restrict__ off,
                                                             const int* __restrict__ csr,
                                                             const unsigned short* __restrict__ Bt,
                                                             const float* __restrict__ bias,
                                                             unsigned short* __restrict__ C,
                                                             int M) {
    constexpr int BM = 64, BN = 256, BK = 32, KS = F / BK;
    constexpr int LDAF = F + 8;               // pad 8 shorts: 2-way aliasing = free
    constexpr int LPR = F / 8;                // lanes per gathered row (16B/lane)
    constexpr int G = 512 / LPR;              // concurrent gather groups
    __shared__ unsigned short Afull[BM * LDAF];
    __shared__ unsigned short Bs[BN * BK];    // 16 KB, swizzled, single buffer
    int tid = threadIdx.x;
    int m0 = blockIdx.x * BM;

    // stage Bs for ks=0 (async DMA; overlaps the gather below)
    #pragma unroll
    for (int it = 0; it < 2; it++) {
        int d = tid + it * 512;                // dest chunk 0..1023 (chunk-linear)
        int r = d >> 2, slot = d & 3;
        int j = (slot - (r >> 1)) & 3;         // source k-chunk for this slot
        gld_lds16(Bt + (size_t)r * F + j * 8, &Bs[d * 8]);
    }

    // gather + aggregate rows m0..m0+63 into Afull
    {
        int gid = tid / LPR, li = tid % LPR;
        int f0 = li * 8;
        for (int n = gid; n < BM; n += G) {
            int node = m0 + n;
            if (node < M) {
                int s = off[node], e = off[node + 1];
                float2 a[4];
                #pragma unroll
                for (int p = 0; p < 4; p++) a[p] = make_float2(0.f, 0.f);
                int i = s;
                for (; i + 4 <= e; i += 4) {
                    int i0 = csr[i], i1 = csr[i + 1], i2 = csr[i + 2], i3 = csr[i + 3];
                    ushort8v r0 = *(const ushort8v*)(H + (size_t)i0 * F + f0);
                    ushort8v r1 = *(const ushort8v*)(H + (size_t)i1 * F + f0);
                    ushort8v r2 = *(const ushort8v*)(H + (size_t)i2 * F + f0);
                    ushort8v r3 = *(const ushort8v*)(H + (size_t)i3 * F + f0);
                    accum16B(a, r0); accum16B(a, r1); accum16B(a, r2); accum16B(a, r3);
                }
                for (; i < e; i++) {
                    ushort8v r0 = *(const ushort8v*)(H + (size_t)csr[i] * F + f0);
                    accum16B(a, r0);
                }
                ushort8v o;
                #pragma unroll
                for (int p = 0; p < 4; p++) { o[2 * p] = f2bf(a[p].x); o[2 * p + 1] = f2bf(a[p].y); }
                *(ushort8v*)&Afull[n * LDAF + f0] = o;
            }
        }
    }
    __syncthreads();   // Afull ready; drains vmcnt -> Bs[ks=0] staged

    int wave = tid >> 6, lane = tid & 63;
    int wm = wave & 1, wn = wave >> 1;        // rows [wm*32,+32), cols [wn*64,+64)
    int mlane = lane & 15, kgrp = lane >> 4;
    floatx4 acc[2][4];
    #pragma unroll
    for (int i = 0; i < 2; i++)
        #pragma unroll
        for (int j = 0; j < 4; j++) acc[i][j] = (floatx4){0.f, 0.f, 0.f, 0.f};

    for (int ks = 0; ks < KS; ks++) {
        short8 af[2], bfr[4];
        #pragma unroll
        for (int nt = 0; nt < 4; nt++) {       // swizzled B fragment read (2-way = free)
            int r = wn * 64 + nt * 16 + mlane;
            int slot = (kgrp + (r >> 1)) & 3;
            bfr[nt] = *(const short8*)&Bs[r * BK + slot * 8];
        }
        #pragma unroll
        for (int mt = 0; mt < 2; mt++)
            af[mt] = *(const short8*)&Afull[(wm * 32 + mt * 16 + mlane) * LDAF + ks * BK + kgrp * 8];
        __syncthreads();                       // all waves done reading Bs[ks]
        if (ks + 1 < KS) {                     // async-stage ks+1; overlaps MFMA below
            #pragma unroll
            for (int it = 0; it < 2; it++) {
                int d = tid + it * 512;
                int r = d >> 2, slot = d & 3;
                int j = (slot - (r >> 1)) & 3;
                gld_lds16(Bt + (size_t)r * F + (ks + 1) * BK + j * 8, &Bs[d * 8]);
            }
        }
        #pragma unroll
        for (int mt = 0; mt < 2; mt++)
            #pragma unroll
            for (int nt = 0; nt < 4; nt++)
                acc[mt][nt] = __builtin_amdgcn_mfma_f32_16x16x32_bf16(af[mt], bfr[nt],
                                                                      acc[mt][nt], 0, 0, 0);
        if (ks + 1 < KS) __syncthreads();      // drain DMA -> Bs[ks+1] valid
    }
    #pragma unroll
    for (int mt = 0; mt < 2; mt++) {
        #pragma unroll
        for (int nt = 0; nt < 4; nt++) {
            int col = wn * 64 + nt * 16 + mlane;
            float bv = bias[col];
            #pragma unroll
            for (int r = 0; r < 4; r++) {
                int row = m0 + wm * 32 + mt * 16 + kgrp * 4 + r;
                if (row < M) {
                    float v = fmaxf(acc[mt][nt][r] + bv, 0.f);
                    C[(size_t)row * BN + col] = f2bf(v);
                }
            }
        }
    }
}

// ---------------- Aggregation F=128 body (used by agg3_mean) ------------------------

__device__ inline void agg128_body(const unsigned short* __restrict__ h,
                                   const int* __restrict__ off,
                                   const int* __restrict__ csr,
                                   int node, int quad, int f0, float2* a) {
    int s = __builtin_amdgcn_readfirstlane(off[node]);
    int e = __builtin_amdgcn_readfirstlane(off[node + 1]);
    int i = s;
    for (; i + 8 <= e; i += 8) {
        ushort8v r[2];
        #pragma unroll
        for (int j = 0; j < 2; j++) {
            int base = i + 4 * j;
            int i0 = csr[base], i1 = csr[base + 1], i2 = csr[base + 2], i3 = csr[base + 3];
            int id = quad == 0 ? i0 : quad == 1 ? i1 : quad == 2 ? i2 : i3;
            r[j] = *(const ushort8v*)(h + (size_t)id * 128 + f0);
        }
        #pragma unroll
        for (int j = 0; j < 2; j++) accum16B(a, r[j]);
    }
    int rem = e - i;
    if (rem > 0) {
        int nr = (rem + 3) >> 2;
        ushort8v r[2];
        #pragma unroll
        for (int j = 0; j < 2; j++) {
            if (j < nr) {
                int base = i + 4 * j;
                int c1 = base + 1 < e ? base + 1 : e - 1;
                int c2 = base + 2 < e ? base + 2 : e - 1;
                int c3 = base + 3 < e ? base + 3 : e - 1;
                int i0 = csr[base], i1 = csr[c1], i2 = csr[c2], i3 = csr[c3];
                int id = quad == 0 ? i0 : quad == 1 ? i1 : quad == 2 ? i2 : i3;
                r[j] = *(const ushort8v*)(h + (size_t)id * 128 + f0);
            }
        }
        #pragma unroll
        for (int j = 0; j < 2; j++) {
            if (j < nr && (i + 4 * j + quad) < e) accum16B(a, r[j]);
        }
    }
    #pragma unroll
    for (int p = 0; p < 4; p++) {
        a[p].x += __shfl_xor(a[p].x, 16, 64);
        a[p].y += __shfl_xor(a[p].y, 16, 64);
        a[p].x += __shfl_xor(a[p].x, 32, 64);
        a[p].y += __shfl_xor(a[p].y, 32, 64);
    }
}

// ---------------- layer-3: quad-split agg + bias + relu + block partial mean -------

__global__ __launch_bounds__(256) void agg3_mean_kernel(const unsigned short* __restrict__ t,
                                                        const int* __restrict__ off,
                                                        const int* __restrict__ csr,
                                                        const float* __restrict__ b3,
                                                        float* __restrict__ partial) {
    __shared__ float sm[4 * 128];
    int wave = threadIdx.x >> 6, lane = threadIdx.x & 63;
    int node = blockIdx.x * 4 + wave;
    int quad = lane >> 4;
    int f0 = (lane & 15) * 8;
    float2 a[4];
    #pragma unroll
    for (int p = 0; p < 4; p++) a[p] = make_float2(0.f, 0.f);
    agg128_body(t, off, csr, node, quad, f0, a);
    if (quad == 0) {
        #pragma unroll
        for (int p = 0; p < 4; p++) {
            sm[wave * 128 + f0 + 2 * p]     = fmaxf(a[p].x + b3[f0 + 2 * p], 0.f);
            sm[wave * 128 + f0 + 2 * p + 1] = fmaxf(a[p].y + b3[f0 + 2 * p + 1], 0.f);
        }
    }
    __syncthreads();
    if (threadIdx.x < 128) {
        int f = threadIdx.x;
        float p = sm[f] + sm[128 + f] + sm[256 + f] + sm[384 + f];
        partial[(size_t)blockIdx.x * 128 + f] = p;
    }
}

__global__ __launch_bounds__(256) void mean_reduce_kernel(const float* __restrict__ partial,
                                                          float* __restrict__ outp, int nRows) {
    __shared__ float s[256];
    int f = threadIdx.x & 127, half = threadIdx.x >> 7;
    int chunk = (nRows + gridDim.x - 1) / gridDim.x;
    int r0 = blockIdx.x * chunk;
    int r1 = r0 + chunk < nRows ? r0 + chunk : nRows;
    float acc = 0.f;
    for (int r = r0 + half; r < r1; r += 2) acc += partial[(size_t)r * 128 + f];
    s[threadIdx.x] = acc;
    __syncthreads();
    if (half == 0) atomicAdd(&outp[f], (s[f] + s[f + 128]) * (1.0f / N_NODES));
}

// ---------------- bf16 MFMA GEMM (gemm3 only): BM=64 x BN=128, 256 thr -------------

template<typename T> __device__ inline void storeC(T* p, float v);
template<> __device__ inline void storeC<float>(float* p, float v) { *p = v; }
template<> __device__ inline void storeC<unsigned short>(unsigned short* p, float v) { *p = f2bf(v); }

template<typename OUT_T>
__global__ __launch_bounds__(256) void gemm_bf16_kernel(const unsigned short* __restrict__ A,
                                                        const unsigned short* __restrict__ Bt,
                                                        const float* __restrict__ bias,
                                                        OUT_T* __restrict__ C,
                                                        int M, int K, int N, int doRelu) {
    constexpr int BM = 64, BN = 128, BK = 32;
    __shared__ unsigned short As[BM * BK];
    __shared__ unsigned short Bs[BN * BK];
    int tid = threadIdx.x;
    int m0 = blockIdx.y * BM, n0 = blockIdx.x * BN;
    int wave = tid >> 6, lane = tid & 63;
    int wm = wave >> 1, wn = wave & 1;
    int mlane = lane & 15, kgrp = lane >> 4;

    floatx4 acc[2][4];
    #pragma unroll
    for (int i = 0; i < 2; i++)
        #pragma unroll
        for (int j = 0; j < 4; j++) acc[i][j] = (floatx4){0.f, 0.f, 0.f, 0.f};

    for (int k0 = 0; k0 < K; k0 += BK) {
        {
            int c = tid;
            int r = c >> 2, cb = (c & 3) * 8;
            gld_lds16(A + (size_t)(m0 + r) * K + k0 + cb, &As[c * 8]);
        }
        #pragma unroll
        for (int it = 0; it < 2; it++) {
            int c = tid + it * 256;
            int r = c >> 2, cb = (c & 3) * 8;
            gld_lds16(Bt + (size_t)(n0 + r) * K + k0 + cb, &Bs[c * 8]);
        }
        __syncthreads();
        short8 af[2], bfr[4];
        #pragma unroll
        for (int mt = 0; mt < 2; mt++)
            af[mt] = *(const short8*)&As[(wm * 32 + mt * 16 + mlane) * BK + kgrp * 8];
        #pragma unroll
        for (int nt = 0; nt < 4; nt++)
            bfr[nt] = *(const short8*)&Bs[(wn * 64 + nt * 16 + mlane) * BK + kgrp * 8];
        #pragma unroll
        for (int mt = 0; mt < 2; mt++)
            #pragma unroll
            for (int nt = 0; nt < 4; nt++)
                acc[mt][nt] = __builtin_amdgcn_mfma_f32_16x16x32_bf16(af[mt], bfr[nt],
                                                                      acc[mt][nt], 0, 0, 0);
        __syncthreads();
    }
    #pragma unroll
    for (int mt = 0; mt < 2; mt++) {
        #pragma unroll
        for (int nt = 0; nt < 4; nt++) {
            int col = n0 + wn * 64 + nt * 16 + mlane;
            float bv = bias ? bias[col] : 0.f;
            #pragma unroll
            for (int r = 0; r < 4; r++) {
                int row = m0 + wm * 32 + mt * 16 + kgrp * 4 + r;
                if (row < M) {
                    float v = acc[mt][nt][r] + bv;
                    if (doRelu) v = fmaxf(v, 0.f);
                    storeC(C + (size_t)row * N + col, v);
                }
            }
        }
    }
}

// ---------------- launch ----------------

extern "C" void kernel_launch(void* const* d_in, const int* in_sizes, int n_in,
                              void* d_out, int out_size, void* d_ws, size_t ws_size,
                              hipStream_t stream) {
    const float* x   = (const float*)d_in[0];
    const int*   src = (const int*)d_in[1];
    const int*   dst = (const int*)d_in[2];
    const float* W1 = (const float*)d_in[3];
    const float* b1 = (const float*)d_in[4];
    const float* W2 = (const float*)d_in[5];
    const float* b2 = (const float*)d_in[6];
    const float* W3 = (const float*)d_in[7];
    const float* b3 = (const float*)d_in[8];
    float* out = (float*)d_out;

    char* ws = (char*)d_ws;
    size_t o = 0;
    auto alloc = [&](size_t bytes) -> char* {
        char* p = ws + o;
        o = (o + bytes + 255) & ~(size_t)255;
        return p;
    };
    int* off     = (int*)alloc((size_t)(N_NODES + 1) * 4);
    int* cur     = (int*)alloc((size_t)N_NODES * 4);
    int* csrIdx  = (int*)alloc((size_t)N_EDGES * 4);
    int* bsum    = (int*)alloc(256 * 4);
    unsigned short* Wt1 = (unsigned short*)alloc((size_t)128 * 256 * 2);
    unsigned short* Wt2 = (unsigned short*)alloc((size_t)256 * 256 * 2);
    unsigned short* Wt3 = (unsigned short*)alloc((size_t)256 * 128 * 2);
    char* R1 = alloc((size_t)N_NODES * 256 * 2);
    char* R2 = alloc((size_t)N_NODES * 256 * 2);
    char* R3 = alloc((size_t)N_NODES * 256 * 2);
    (void)alloc(65536);   // guard region for gemm3 tail-block over-reads past R3

    unsigned short* xb    = (unsigned short*)R1;  // 50000x128 bf16
    unsigned short* h1    = (unsigned short*)R3;  // 50000x256 bf16
    unsigned short* h2    = (unsigned short*)R2;  // 50000x256 bf16
    unsigned short* t     = (unsigned short*)R3;  // 50000x128 bf16 (h1 dead by then)
    float*          pmean = (float*)R1;           // 12500x128 fp32 (xb dead by then)

    const int nb = (N_NODES + 255) / 256;  // 196

    hipMemsetAsync(cur, 0, (size_t)N_NODES * 4, stream);
    const int hpThreads = N_EDGES + 131072 + N_NODES * 128 / 4;
    histprep_kernel<<<(hpThreads + 255) / 256, 256, 0, stream>>>(dst, cur, W1, W2, W3, x,
                                                                 Wt1, Wt2, Wt3, xb, bsum, out);
    scan_onepass_kernel<<<nb, 256, 0, stream>>>(cur, bsum, off, N_NODES);
    fill_kernel<<<(N_EDGES + 255) / 256, 256, 0, stream>>>(src, dst, cur, csrIdx, N_EDGES);

    const int mbF = (N_NODES + 63) / 64;  // 782

    // Layer 1 fused: h1 = relu(agg(xb) @ W1 + b1)
    fused_agg_gemm_kernel<128><<<mbF, 512, 0, stream>>>(xb, off, csrIdx, Wt1, b1, h1, N_NODES);
    // Layer 2 fused: h2 = relu(agg(h1) @ W2 + b2)
    fused_agg_gemm_kernel<256><<<mbF, 512, 0, stream>>>(h1, off, csrIdx, Wt2, b2, h2, N_NODES);
    // Layer 3 reordered: t = h2 @ W3 (bf16), then fused agg+bias+relu+partial-mean
    gemm_bf16_kernel<unsigned short><<<dim3(1, mbF), 256, 0, stream>>>(h2, Wt3, nullptr, t,
                                                                       N_NODES, 256, 128, 0);
    agg3_mean_kernel<<<N_NODES / 4, 256, 0, stream>>>(t, off, csrIdx, b3, pmean);
    mean_reduce_kernel<<<128, 256, 0, stream>>>(pmean, out, N_NODES / 4);
}

// Round 13
// 288.439 us; speedup vs baseline: 1.1116x; 1.0261x over previous
//
#include <hip/hip_runtime.h>

#define N_NODES 50000
#define N_EDGES 500000

typedef __attribute__((ext_vector_type(8))) short short8;
typedef __attribute__((ext_vector_type(8))) unsigned short ushort8v;
typedef __attribute__((ext_vector_type(4))) float floatx4;
typedef __attribute__((ext_vector_type(4))) unsigned int uint4v;

__device__ inline float bf2f(unsigned short u) {
    unsigned int x = ((unsigned int)u) << 16;
    return __builtin_bit_cast(float, x);
}
__device__ inline unsigned short f2bf(float f) {  // round-to-nearest-even
    unsigned int x = __builtin_bit_cast(unsigned int, f);
    x += 0x7fff + ((x >> 16) & 1);
    return (unsigned short)(x >> 16);
}

// async 16B global -> LDS; LDS dest must be wave-uniform base + lane*16
__device__ __forceinline__ void gld_lds16(const unsigned short* g, unsigned short* l) {
    __builtin_amdgcn_global_load_lds((const __attribute__((address_space(1))) void*)g,
                                     (__attribute__((address_space(3))) void*)l, 16, 0, 0);
}

// accumulate 8 bf16 (16B) into 4 float2 pairs: lo = u<<16, hi = u & 0xFFFF0000
__device__ inline void accum16B(float2* a, ushort8v rv) {
    uint4v u = __builtin_bit_cast(uint4v, rv);
    #pragma unroll
    for (int p = 0; p < 4; p++) {
        float lo = __builtin_bit_cast(float, u[p] << 16);
        float hi = __builtin_bit_cast(float, u[p] & 0xFFFF0000u);
        a[p].x += lo;
        a[p].y += hi;
    }
}

// ---------------- merged hist + prep + zero(bsum,out) ----------------

__global__ __launch_bounds__(256) void histprep_kernel(const int* __restrict__ dst,
                                                       int* __restrict__ deg,
                                                       const float* __restrict__ W1,
                                                       const float* __restrict__ W2,
                                                       const float* __restrict__ W3,
                                                       const float* __restrict__ x,
                                                       unsigned short* __restrict__ Wt1,
                                                       unsigned short* __restrict__ Wt2,
                                                       unsigned short* __restrict__ Wt3,
                                                       unsigned short* __restrict__ xb,
                                                       int* __restrict__ bsum,
                                                       float* __restrict__ outZ) {
    int idx = blockIdx.x * 256 + threadIdx.x;
    if (idx < N_EDGES) { atomicAdd(&deg[dst[idx]], 1); return; }
    idx -= N_EDGES;
    if (idx < 32768) {
        if (idx < 256) bsum[idx] = 0;       // zero scan publication slots
        if (idx < 128) outZ[idx] = 0.f;     // zero final output (poisoned each call)
        int k = idx >> 8, n = idx & 255;
        Wt1[n * 128 + k] = f2bf(W1[idx]);
    } else if (idx < 98304) {
        int i = idx - 32768;
        int k = i >> 8, n = i & 255;
        Wt2[n * 256 + k] = f2bf(W2[i]);
    } else if (idx < 131072) {
        int i = idx - 98304;
        int k = i >> 7, n = i & 127;
        Wt3[n * 256 + k] = f2bf(W3[i]);
    } else {
        int i = (idx - 131072) * 4;
        if (i < N_NODES * 128) {
            float4 v = *(const float4*)(x + i);
            ushort4 o;
            o.x = f2bf(v.x); o.y = f2bf(v.y); o.z = f2bf(v.z); o.w = f2bf(v.w);
            *(ushort4*)(xb + i) = o;
        }
    }
}

// ---------------- single-pass scan + finalize ----------------

__global__ __launch_bounds__(256) void scan_onepass_kernel(int* __restrict__ cur,
                                                           int* __restrict__ bsum,
                                                           int* __restrict__ off, int n) {
    __shared__ int s[256];
    int b = blockIdx.x, t = threadIdx.x;
    int i = b * 256 + t;
    int v = (i < n) ? cur[i] : 0;
    s[t] = v;
    __syncthreads();
    #pragma unroll
    for (int d = 1; d < 256; d <<= 1) {
        int u = (t >= d) ? s[t - d] : 0;
        __syncthreads();
        s[t] += u;
        __syncthreads();
    }
    int incl = s[t];
    if (t == 255) atomicExch(&bsum[b], s[255] + 1);   // publish (value+1, nonzero flag)
    int pre = 0;
    if (t < b) {
        volatile int* p = (volatile int*)&bsum[t];
        int vv;
        while ((vv = *p) == 0) { }
        pre = vv - 1;
    }
    __syncthreads();
    s[t] = pre;
    __syncthreads();
    #pragma unroll
    for (int d = 128; d > 0; d >>= 1) {
        if (t < d) s[t] += s[t + d];
        __syncthreads();
    }
    int base = s[0];
    if (i == 0) off[0] = 0;
    if (i < n) {
        int inclG = base + incl;
        off[i + 1] = inclG;
        cur[i] = inclG - v;   // cur held deg; now row start
    }
}

__global__ void fill_kernel(const int* __restrict__ src, const int* __restrict__ dst,
                            int* __restrict__ cur, int* __restrict__ csr, int nE) {
    int e = blockIdx.x * 256 + threadIdx.x;
    if (e < nE) {
        int p = atomicAdd(&cur[dst[e]], 1);
        csr[p] = src[e];
    }
}

// ---------------- fused agg + GEMM (v4): deep-ILP gather ---------------------------
// Block: 512 thr (8 waves), BM=64, BN=256 (=N). A gathered once into padded LDS.
// Gather keeps 8 edge-loads in flight per group (16/wave, 2x r12) via two
// independent accumulator sets; tail = 4-batch + clamped predicated 4-batch.
// B: single 16 KB swizzled LDS buffer (r12), async-staged, 2 barriers/k-step.

template<int F>
__global__ __launch_bounds__(512) void fused_agg_gemm_kernel(const unsigned short* __restrict__ H,
                                                             const int* __restrict__ off,
                                                             const int* __restrict__ csr,
                                                             const unsigned short* __restrict__ Bt,
                                                             const float* __restrict__ bias,
                                                             unsigned short* __restrict__ C,
                                                             int M) {
    constexpr int BM = 64, BN = 256, BK = 32, KS = F / BK;
    constexpr int LDAF = F + 8;               // pad 8 shorts: 2-way aliasing = free
    constexpr int LPR = F / 8;                // lanes per gathered row (16B/lane)
    constexpr int G = 512 / LPR;              // concurrent gather groups
    __shared__ unsigned short Afull[BM * LDAF];
    __shared__ unsigned short Bs[BN * BK];    // 16 KB, swizzled, single buffer
    int tid = threadIdx.x;
    int m0 = blockIdx.x * BM;

    // stage Bs for ks=0 (async DMA; overlaps the gather below)
    #pragma unroll
    for (int it = 0; it < 2; it++) {
        int d = tid + it * 512;                // dest chunk 0..1023 (chunk-linear)
        int r = d >> 2, slot = d & 3;
        int j = (slot - (r >> 1)) & 3;         // source k-chunk for this slot
        gld_lds16(Bt + (size_t)r * F + j * 8, &Bs[d * 8]);
    }

    // gather + aggregate rows m0..m0+63 into Afull — 8 loads in flight per group
    {
        int gid = tid / LPR, li = tid % LPR;
        int f0 = li * 8;
        for (int n = gid; n < BM; n += G) {
            int node = m0 + n;
            if (node < M) {
                int s = off[node], e = off[node + 1];
                float2 a[4], b[4];
                #pragma unroll
                for (int p = 0; p < 4; p++) {
                    a[p] = make_float2(0.f, 0.f);
                    b[p] = make_float2(0.f, 0.f);
                }
                int i = s;
                for (; i + 8 <= e; i += 8) {   // 8 loads issued back-to-back
                    ushort8v r[8];
                    #pragma unroll
                    for (int j = 0; j < 8; j++)
                        r[j] = *(const ushort8v*)(H + (size_t)csr[i + j] * F + f0);
                    #pragma unroll
                    for (int j = 0; j < 4; j++) accum16B(a, r[j]);
                    #pragma unroll
                    for (int j = 4; j < 8; j++) accum16B(b, r[j]);
                }
                if (i + 4 <= e) {              // unconditional 4-batch
                    ushort8v r[4];
                    #pragma unroll
                    for (int j = 0; j < 4; j++)
                        r[j] = *(const ushort8v*)(H + (size_t)csr[i + j] * F + f0);
                    #pragma unroll
                    for (int j = 0; j < 4; j++) accum16B(a, r[j]);
                    i += 4;
                }
                if (i < e) {                   // clamped predicated 4-batch (rem 1..3)
                    ushort8v r[4];
                    #pragma unroll
                    for (int j = 0; j < 4; j++) {
                        int ii = i + j < e ? i + j : e - 1;
                        r[j] = *(const ushort8v*)(H + (size_t)csr[ii] * F + f0);
                    }
                    #pragma unroll
                    for (int j = 0; j < 4; j++)
                        if (i + j < e) accum16B(b, r[j]);
                }
                ushort8v o;
                #pragma unroll
                for (int p = 0; p < 4; p++) {
                    o[2 * p]     = f2bf(a[p].x + b[p].x);
                    o[2 * p + 1] = f2bf(a[p].y + b[p].y);
                }
                *(ushort8v*)&Afull[n * LDAF + f0] = o;
            }
        }
    }
    __syncthreads();   // Afull ready; drains vmcnt -> Bs[ks=0] staged

    int wave = tid >> 6, lane = tid & 63;
    int wm = wave & 1, wn = wave >> 1;        // rows [wm*32,+32), cols [wn*64,+64)
    int mlane = lane & 15, kgrp = lane >> 4;
    floatx4 acc[2][4];
    #pragma unroll
    for (int i = 0; i < 2; i++)
        #pragma unroll
        for (int j = 0; j < 4; j++) acc[i][j] = (floatx4){0.f, 0.f, 0.f, 0.f};

    for (int ks = 0; ks < KS; ks++) {
        short8 af[2], bfr[4];
        #pragma unroll
        for (int nt = 0; nt < 4; nt++) {       // swizzled B fragment read (2-way = free)
            int r = wn * 64 + nt * 16 + mlane;
            int slot = (kgrp + (r >> 1)) & 3;
            bfr[nt] = *(const short8*)&Bs[r * BK + slot * 8];
        }
        #pragma unroll
        for (int mt = 0; mt < 2; mt++)
            af[mt] = *(const short8*)&Afull[(wm * 32 + mt * 16 + mlane) * LDAF + ks * BK + kgrp * 8];
        __syncthreads();                       // all waves done reading Bs[ks]
        if (ks + 1 < KS) {                     // async-stage ks+1; overlaps MFMA below
            #pragma unroll
            for (int it = 0; it < 2; it++) {
                int d = tid + it * 512;
                int r = d >> 2, slot = d & 3;
                int j = (slot - (r >> 1)) & 3;
                gld_lds16(Bt + (size_t)r * F + (ks + 1) * BK + j * 8, &Bs[d * 8]);
            }
        }
        #pragma unroll
        for (int mt = 0; mt < 2; mt++)
            #pragma unroll
            for (int nt = 0; nt < 4; nt++)
                acc[mt][nt] = __builtin_amdgcn_mfma_f32_16x16x32_bf16(af[mt], bfr[nt],
                                                                      acc[mt][nt], 0, 0, 0);
        if (ks + 1 < KS) __syncthreads();      // drain DMA -> Bs[ks+1] valid
    }
    #pragma unroll
    for (int mt = 0; mt < 2; mt++) {
        #pragma unroll
        for (int nt = 0; nt < 4; nt++) {
            int col = wn * 64 + nt * 16 + mlane;
            float bv = bias[col];
            #pragma unroll
            for (int r = 0; r < 4; r++) {
                int row = m0 + wm * 32 + mt * 16 + kgrp * 4 + r;
                if (row < M) {
                    float v = fmaxf(acc[mt][nt][r] + bv, 0.f);
                    C[(size_t)row * BN + col] = f2bf(v);
                }
            }
        }
    }
}

// ---------------- Aggregation F=128 body (used by agg3_mean) ------------------------

__device__ inline void agg128_body(const unsigned short* __restrict__ h,
                                   const int* __restrict__ off,
                                   const int* __restrict__ csr,
                                   int node, int quad, int f0, float2* a) {
    int s = __builtin_amdgcn_readfirstlane(off[node]);
    int e = __builtin_amdgcn_readfirstlane(off[node + 1]);
    int i = s;
    for (; i + 8 <= e; i += 8) {
        ushort8v r[2];
        #pragma unroll
        for (int j = 0; j < 2; j++) {
            int base = i + 4 * j;
            int i0 = csr[base], i1 = csr[base + 1], i2 = csr[base + 2], i3 = csr[base + 3];
            int id = quad == 0 ? i0 : quad == 1 ? i1 : quad == 2 ? i2 : i3;
            r[j] = *(const ushort8v*)(h + (size_t)id * 128 + f0);
        }
        #pragma unroll
        for (int j = 0; j < 2; j++) accum16B(a, r[j]);
    }
    int rem = e - i;
    if (rem > 0) {
        int nr = (rem + 3) >> 2;
        ushort8v r[2];
        #pragma unroll
        for (int j = 0; j < 2; j++) {
            if (j < nr) {
                int base = i + 4 * j;
                int c1 = base + 1 < e ? base + 1 : e - 1;
                int c2 = base + 2 < e ? base + 2 : e - 1;
                int c3 = base + 3 < e ? base + 3 : e - 1;
                int i0 = csr[base], i1 = csr[c1], i2 = csr[c2], i3 = csr[c3];
                int id = quad == 0 ? i0 : quad == 1 ? i1 : quad == 2 ? i2 : i3;
                r[j] = *(const ushort8v*)(h + (size_t)id * 128 + f0);
            }
        }
        #pragma unroll
        for (int j = 0; j < 2; j++) {
            if (j < nr && (i + 4 * j + quad) < e) accum16B(a, r[j]);
        }
    }
    #pragma unroll
    for (int p = 0; p < 4; p++) {
        a[p].x += __shfl_xor(a[p].x, 16, 64);
        a[p].y += __shfl_xor(a[p].y, 16, 64);
        a[p].x += __shfl_xor(a[p].x, 32, 64);
        a[p].y += __shfl_xor(a[p].y, 32, 64);
    }
}

// ---------------- layer-3: quad-split agg + bias + relu + block partial mean -------

__global__ __launch_bounds__(256) void agg3_mean_kernel(const unsigned short* __restrict__ t,
                                                        const int* __restrict__ off,
                                                        const int* __restrict__ csr,
                                                        const float* __restrict__ b3,
                                                        float* __restrict__ partial) {
    __shared__ float sm[4 * 128];
    int wave = threadIdx.x >> 6, lane = threadIdx.x & 63;
    int node = blockIdx.x * 4 + wave;
    int quad = lane >> 4;
    int f0 = (lane & 15) * 8;
    float2 a[4];
    #pragma unroll
    for (int p = 0; p < 4; p++) a[p] = make_float2(0.f, 0.f);
    agg128_body(t, off, csr, node, quad, f0, a);
    if (quad == 0) {
        #pragma unroll
        for (int p = 0; p < 4; p++) {
            sm[wave * 128 + f0 + 2 * p]     = fmaxf(a[p].x + b3[f0 + 2 * p], 0.f);
            sm[wave * 128 + f0 + 2 * p + 1] = fmaxf(a[p].y + b3[f0 + 2 * p + 1], 0.f);
        }
    }
    __syncthreads();
    if (threadIdx.x < 128) {
        int f = threadIdx.x;
        float p = sm[f] + sm[128 + f] + sm[256 + f] + sm[384 + f];
        partial[(size_t)blockIdx.x * 128 + f] = p;
    }
}

__global__ __launch_bounds__(256) void mean_reduce_kernel(const float* __restrict__ partial,
                                                          float* __restrict__ outp, int nRows) {
    __shared__ float s[256];
    int f = threadIdx.x & 127, half = threadIdx.x >> 7;
    int chunk = (nRows + gridDim.x - 1) / gridDim.x;
    int r0 = blockIdx.x * chunk;
    int r1 = r0 + chunk < nRows ? r0 + chunk : nRows;
    float acc = 0.f;
    for (int r = r0 + half; r < r1; r += 2) acc += partial[(size_t)r * 128 + f];
    s[threadIdx.x] = acc;
    __syncthreads();
    if (half == 0) atomicAdd(&outp[f], (s[f] + s[f + 128]) * (1.0f / N_NODES));
}

// ---------------- bf16 MFMA GEMM (gemm3 only): BM=64 x BN=128, 256 thr -------------

template<typename T> __device__ inline void storeC(T* p, float v);
template<> __device__ inline void storeC<float>(float* p, float v) { *p = v; }
template<> __device__ inline void storeC<unsigned short>(unsigned short* p, float v) { *p = f2bf(v); }

template<typename OUT_T>
__global__ __launch_bounds__(256) void gemm_bf16_kernel(const unsigned short* __restrict__ A,
                                                        const unsigned short* __restrict__ Bt,
                                                        const float* __restrict__ bias,
                                                        OUT_T* __restrict__ C,
                                                        int M, int K, int N, int doRelu) {
    constexpr int BM = 64, BN = 128, BK = 32;
    __shared__ unsigned short As[BM * BK];
    __shared__ unsigned short Bs[BN * BK];
    int tid = threadIdx.x;
    int m0 = blockIdx.y * BM, n0 = blockIdx.x * BN;
    int wave = tid >> 6, lane = tid & 63;
    int wm = wave >> 1, wn = wave & 1;
    int mlane = lane & 15, kgrp = lane >> 4;

    floatx4 acc[2][4];
    #pragma unroll
    for (int i = 0; i < 2; i++)
        #pragma unroll
        for (int j = 0; j < 4; j++) acc[i][j] = (floatx4){0.f, 0.f, 0.f, 0.f};

    for (int k0 = 0; k0 < K; k0 += BK) {
        {
            int c = tid;
            int r = c >> 2, cb = (c & 3) * 8;
            gld_lds16(A + (size_t)(m0 + r) * K + k0 + cb, &As[c * 8]);
        }
        #pragma unroll
        for (int it = 0; it < 2; it++) {
            int c = tid + it * 256;
            int r = c >> 2, cb = (c & 3) * 8;
            gld_lds16(Bt + (size_t)(n0 + r) * K + k0 + cb, &Bs[c * 8]);
        }
        __syncthreads();
        short8 af[2], bfr[4];
        #pragma unroll
        for (int mt = 0; mt < 2; mt++)
            af[mt] = *(const short8*)&As[(wm * 32 + mt * 16 + mlane) * BK + kgrp * 8];
        #pragma unroll
        for (int nt = 0; nt < 4; nt++)
            bfr[nt] = *(const short8*)&Bs[(wn * 64 + nt * 16 + mlane) * BK + kgrp * 8];
        #pragma unroll
        for (int mt = 0; mt < 2; mt++)
            #pragma unroll
            for (int nt = 0; nt < 4; nt++)
                acc[mt][nt] = __builtin_amdgcn_mfma_f32_16x16x32_bf16(af[mt], bfr[nt],
                                                                      acc[mt][nt], 0, 0, 0);
        __syncthreads();
    }
    #pragma unroll
    for (int mt = 0; mt < 2; mt++) {
        #pragma unroll
        for (int nt = 0; nt < 4; nt++) {
            int col = n0 + wn * 64 + nt * 16 + mlane;
            float bv = bias ? bias[col] : 0.f;
            #pragma unroll
            for (int r = 0; r < 4; r++) {
                int row = m0 + wm * 32 + mt * 16 + kgrp * 4 + r;
                if (row < M) {
                    float v = acc[mt][nt][r] + bv;
                    if (doRelu) v = fmaxf(v, 0.f);
                    storeC(C + (size_t)row * N + col, v);
                }
            }
        }
    }
}

// ---------------- launch ----------------

extern "C" void kernel_launch(void* const* d_in, const int* in_sizes, int n_in,
                              void* d_out, int out_size, void* d_ws, size_t ws_size,
                              hipStream_t stream) {
    const float* x   = (const float*)d_in[0];
    const int*   src = (const int*)d_in[1];
    const int*   dst = (const int*)d_in[2];
    const float* W1 = (const float*)d_in[3];
    const float* b1 = (const float*)d_in[4];
    const float* W2 = (const float*)d_in[5];
    const float* b2 = (const float*)d_in[6];
    const float* W3 = (const float*)d_in[7];
    const float* b3 = (const float*)d_in[8];
    float* out = (float*)d_out;

    char* ws = (char*)d_ws;
    size_t o = 0;
    auto alloc = [&](size_t bytes) -> char* {
        char* p = ws + o;
        o = (o + bytes + 255) & ~(size_t)255;
        return p;
    };
    int* off     = (int*)alloc((size_t)(N_NODES + 1) * 4);
    int* cur     = (int*)alloc((size_t)N_NODES * 4);
    int* csrIdx  = (int*)alloc((size_t)N_EDGES * 4);
    int* bsum    = (int*)alloc(256 * 4);
    unsigned short* Wt1 = (unsigned short*)alloc((size_t)128 * 256 * 2);
    unsigned short* Wt2 = (unsigned short*)alloc((size_t)256 * 256 * 2);
    unsigned short* Wt3 = (unsigned short*)alloc((size_t)256 * 128 * 2);
    char* R1 = alloc((size_t)N_NODES * 256 * 2);
    char* R2 = alloc((size_t)N_NODES * 256 * 2);
    char* R3 = alloc((size_t)N_NODES * 256 * 2);
    (void)alloc(65536);   // guard region for gemm3 tail-block over-reads past R3

    unsigned short* xb    = (unsigned short*)R1;  // 50000x128 bf16
    unsigned short* h1    = (unsigned short*)R3;  // 50000x256 bf16
    unsigned short* h2    = (unsigned short*)R2;  // 50000x256 bf16
    unsigned short* t     = (unsigned short*)R3;  // 50000x128 bf16 (h1 dead by then)
    float*          pmean = (float*)R1;           // 12500x128 fp32 (xb dead by then)

    const int nb = (N_NODES + 255) / 256;  // 196

    hipMemsetAsync(cur, 0, (size_t)N_NODES * 4, stream);
    const int hpThreads = N_EDGES + 131072 + N_NODES * 128 / 4;
    histprep_kernel<<<(hpThreads + 255) / 256, 256, 0, stream>>>(dst, cur, W1, W2, W3, x,
                                                                 Wt1, Wt2, Wt3, xb, bsum, out);
    scan_onepass_kernel<<<nb, 256, 0, stream>>>(cur, bsum, off, N_NODES);
    fill_kernel<<<(N_EDGES + 255) / 256, 256, 0, stream>>>(src, dst, cur, csrIdx, N_EDGES);

    const int mbF = (N_NODES + 63) / 64;  // 782

    // Layer 1 fused: h1 = relu(agg(xb) @ W1 + b1)
    fused_agg_gemm_kernel<128><<<mbF, 512, 0, stream>>>(xb, off, csrIdx, Wt1, b1, h1, N_NODES);
    // Layer 2 fused: h2 = relu(agg(h1) @ W2 + b2)
    fused_agg_gemm_kernel<256><<<mbF, 512, 0, stream>>>(h1, off, csrIdx, Wt2, b2, h2, N_NODES);
    // Layer 3 reordered: t = h2 @ W3 (bf16), then fused agg+bias+relu+partial-mean
    gemm_bf16_kernel<unsigned short><<<dim3(1, mbF), 256, 0, stream>>>(h2, Wt3, nullptr, t,
                                                                       N_NODES, 256, 128, 0);
    agg3_mean_kernel<<<N_NODES / 4, 256, 0, stream>>>(t, off, csrIdx, b3, pmean);
    mean_reduce_kernel<<<128, 256, 0, stream>>>(pmean, out, N_NODES / 4);
}

// Round 14
// 278.873 us; speedup vs baseline: 1.1498x; 1.0343x over previous
//
#include <hip/hip_runtime.h>

#define N_NODES 50000
#define N_EDGES 500000

typedef __attribute__((ext_vector_type(8))) short short8;
typedef __attribute__((ext_vector_type(8))) unsigned short ushort8v;
typedef __attribute__((ext_vector_type(4))) float floatx4;
typedef __attribute__((ext_vector_type(4))) unsigned int uint4v;

__device__ inline float bf2f(unsigned short u) {
    unsigned int x = ((unsigned int)u) << 16;
    return __builtin_bit_cast(float, x);
}
__device__ inline unsigned short f2bf(float f) {  // round-to-nearest-even
    unsigned int x = __builtin_bit_cast(unsigned int, f);
    x += 0x7fff + ((x >> 16) & 1);
    return (unsigned short)(x >> 16);
}

// async 16B global -> LDS; LDS dest must be wave-uniform base + lane*16
__device__ __forceinline__ void gld_lds16(const unsigned short* g, unsigned short* l) {
    __builtin_amdgcn_global_load_lds((const __attribute__((address_space(1))) void*)g,
                                     (__attribute__((address_space(3))) void*)l, 16, 0, 0);
}

// accumulate 8 bf16 (16B) into 4 float2 pairs: lo = u<<16, hi = u & 0xFFFF0000
__device__ inline void accum16B(float2* a, ushort8v rv) {
    uint4v u = __builtin_bit_cast(uint4v, rv);
    #pragma unroll
    for (int p = 0; p < 4; p++) {
        float lo = __builtin_bit_cast(float, u[p] << 16);
        float hi = __builtin_bit_cast(float, u[p] & 0xFFFF0000u);
        a[p].x += lo;
        a[p].y += hi;
    }
}

// ---------------- merged hist + prep + zero(bsum,out) ----------------

__global__ __launch_bounds__(256) void histprep_kernel(const int* __restrict__ dst,
                                                       int* __restrict__ deg,
                                                       const float* __restrict__ W1,
                                                       const float* __restrict__ W2,
                                                       const float* __restrict__ W3,
                                                       const float* __restrict__ x,
                                                       unsigned short* __restrict__ Wt1,
                                                       unsigned short* __restrict__ Wt2,
                                                       unsigned short* __restrict__ Wt3,
                                                       unsigned short* __restrict__ xb,
                                                       int* __restrict__ bsum,
                                                       float* __restrict__ outZ) {
    int idx = blockIdx.x * 256 + threadIdx.x;
    if (idx < N_EDGES) { atomicAdd(&deg[dst[idx]], 1); return; }
    idx -= N_EDGES;
    if (idx < 32768) {
        if (idx < 256) bsum[idx] = 0;       // zero scan publication slots
        if (idx < 128) outZ[idx] = 0.f;     // zero final output (poisoned each call)
        int k = idx >> 8, n = idx & 255;
        Wt1[n * 128 + k] = f2bf(W1[idx]);
    } else if (idx < 98304) {
        int i = idx - 32768;
        int k = i >> 8, n = i & 255;
        Wt2[n * 256 + k] = f2bf(W2[i]);
    } else if (idx < 131072) {
        int i = idx - 98304;
        int k = i >> 7, n = i & 127;
        Wt3[n * 256 + k] = f2bf(W3[i]);
    } else {
        int i = (idx - 131072) * 4;
        if (i < N_NODES * 128) {
            float4 v = *(const float4*)(x + i);
            ushort4 o;
            o.x = f2bf(v.x); o.y = f2bf(v.y); o.z = f2bf(v.z); o.w = f2bf(v.w);
            *(ushort4*)(xb + i) = o;
        }
    }
}

// ---------------- single-pass scan + finalize ----------------

__global__ __launch_bounds__(256) void scan_onepass_kernel(int* __restrict__ cur,
                                                           int* __restrict__ bsum,
                                                           int* __restrict__ off, int n) {
    __shared__ int s[256];
    int b = blockIdx.x, t = threadIdx.x;
    int i = b * 256 + t;
    int v = (i < n) ? cur[i] : 0;
    s[t] = v;
    __syncthreads();
    #pragma unroll
    for (int d = 1; d < 256; d <<= 1) {
        int u = (t >= d) ? s[t - d] : 0;
        __syncthreads();
        s[t] += u;
        __syncthreads();
    }
    int incl = s[t];
    if (t == 255) atomicExch(&bsum[b], s[255] + 1);   // publish (value+1, nonzero flag)
    int pre = 0;
    if (t < b) {
        volatile int* p = (volatile int*)&bsum[t];
        int vv;
        while ((vv = *p) == 0) { }
        pre = vv - 1;
    }
    __syncthreads();
    s[t] = pre;
    __syncthreads();
    #pragma unroll
    for (int d = 128; d > 0; d >>= 1) {
        if (t < d) s[t] += s[t + d];
        __syncthreads();
    }
    int base = s[0];
    if (i == 0) off[0] = 0;
    if (i < n) {
        int inclG = base + incl;
        off[i + 1] = inclG;
        cur[i] = inclG - v;   // cur held deg; now row start
    }
}

__global__ void fill_kernel(const int* __restrict__ src, const int* __restrict__ dst,
                            int* __restrict__ cur, int* __restrict__ csr, int nE) {
    int e = blockIdx.x * 256 + threadIdx.x;
    if (e < nE) {
        int p = atomicAdd(&cur[dst[e]], 1);
        csr[p] = src[e];
    }
}

// ---------------- fused agg + GEMM (v5) --------------------------------------------
// Block: 512 thr (8 waves), BM=64, BN=256 (=N). A gathered once into padded LDS
// (deep-ILP: 8 loads in flight/group). B: single 16 KB swizzled LDS buffer.
// FUSE_T (layer 2+3): instead of writing h2, the relu(h2+b2) tile is written
// back into the freed Afull LDS and multiplied by W3t (global, L2-hot) to emit
// t = relu(h2+b2) @ W3 directly — h2 never touches HBM, gemm3 dispatch deleted.

template<int F, bool FUSE_T>
__global__ __launch_bounds__(512) void fused_agg_gemm_kernel(const unsigned short* __restrict__ H,
                                                             const int* __restrict__ off,
                                                             const int* __restrict__ csr,
                                                             const unsigned short* __restrict__ Bt,
                                                             const float* __restrict__ bias,
                                                             unsigned short* __restrict__ C,
                                                             const unsigned short* __restrict__ W3t,
                                                             unsigned short* __restrict__ tOut,
                                                             int M) {
    constexpr int BM = 64, BN = 256, BK = 32, KS = F / BK;
    constexpr int LDAF = F + 8;               // pad 8 shorts: 2-way aliasing = free
    constexpr int LPR = F / 8;                // lanes per gathered row (16B/lane)
    constexpr int G = 512 / LPR;              // concurrent gather groups
    __shared__ unsigned short Afull[BM * LDAF];
    __shared__ unsigned short Bs[BN * BK];    // 16 KB, swizzled, single buffer
    int tid = threadIdx.x;
    int m0 = blockIdx.x * BM;

    // stage Bs for ks=0 (async DMA; overlaps the gather below)
    #pragma unroll
    for (int it = 0; it < 2; it++) {
        int d = tid + it * 512;                // dest chunk 0..1023 (chunk-linear)
        int r = d >> 2, slot = d & 3;
        int j = (slot - (r >> 1)) & 3;         // source k-chunk for this slot
        gld_lds16(Bt + (size_t)r * F + j * 8, &Bs[d * 8]);
    }

    // gather + aggregate rows m0..m0+63 into Afull — 8 loads in flight per group
    {
        int gid = tid / LPR, li = tid % LPR;
        int f0 = li * 8;
        for (int n = gid; n < BM; n += G) {
            int node = m0 + n;
            if (node < M) {
                int s = off[node], e = off[node + 1];
                float2 a[4], b[4];
                #pragma unroll
                for (int p = 0; p < 4; p++) {
                    a[p] = make_float2(0.f, 0.f);
                    b[p] = make_float2(0.f, 0.f);
                }
                int i = s;
                for (; i + 8 <= e; i += 8) {   // 8 loads issued back-to-back
                    ushort8v r[8];
                    #pragma unroll
                    for (int j = 0; j < 8; j++)
                        r[j] = *(const ushort8v*)(H + (size_t)csr[i + j] * F + f0);
                    #pragma unroll
                    for (int j = 0; j < 4; j++) accum16B(a, r[j]);
                    #pragma unroll
                    for (int j = 4; j < 8; j++) accum16B(b, r[j]);
                }
                if (i + 4 <= e) {              // unconditional 4-batch
                    ushort8v r[4];
                    #pragma unroll
                    for (int j = 0; j < 4; j++)
                        r[j] = *(const ushort8v*)(H + (size_t)csr[i + j] * F + f0);
                    #pragma unroll
                    for (int j = 0; j < 4; j++) accum16B(a, r[j]);
                    i += 4;
                }
                if (i < e) {                   // clamped predicated 4-batch (rem 1..3)
                    ushort8v r[4];
                    #pragma unroll
                    for (int j = 0; j < 4; j++) {
                        int ii = i + j < e ? i + j : e - 1;
                        r[j] = *(const ushort8v*)(H + (size_t)csr[ii] * F + f0);
                    }
                    #pragma unroll
                    for (int j = 0; j < 4; j++)
                        if (i + j < e) accum16B(b, r[j]);
                }
                ushort8v o;
                #pragma unroll
                for (int p = 0; p < 4; p++) {
                    o[2 * p]     = f2bf(a[p].x + b[p].x);
                    o[2 * p + 1] = f2bf(a[p].y + b[p].y);
                }
                *(ushort8v*)&Afull[n * LDAF + f0] = o;
            }
        }
    }
    __syncthreads();   // Afull ready; drains vmcnt -> Bs[ks=0] staged

    int wave = tid >> 6, lane = tid & 63;
    int wm = wave & 1, wn = wave >> 1;        // rows [wm*32,+32), cols [wn*64,+64)
    int mlane = lane & 15, kgrp = lane >> 4;
    floatx4 acc[2][4];
    #pragma unroll
    for (int i = 0; i < 2; i++)
        #pragma unroll
        for (int j = 0; j < 4; j++) acc[i][j] = (floatx4){0.f, 0.f, 0.f, 0.f};

    for (int ks = 0; ks < KS; ks++) {
        short8 af[2], bfr[4];
        #pragma unroll
        for (int nt = 0; nt < 4; nt++) {       // swizzled B fragment read (2-way = free)
            int r = wn * 64 + nt * 16 + mlane;
            int slot = (kgrp + (r >> 1)) & 3;
            bfr[nt] = *(const short8*)&Bs[r * BK + slot * 8];
        }
        #pragma unroll
        for (int mt = 0; mt < 2; mt++)
            af[mt] = *(const short8*)&Afull[(wm * 32 + mt * 16 + mlane) * LDAF + ks * BK + kgrp * 8];
        __syncthreads();                       // all waves done reading Bs[ks]
        if (ks + 1 < KS) {                     // async-stage ks+1; overlaps MFMA below
            #pragma unroll
            for (int it = 0; it < 2; it++) {
                int d = tid + it * 512;
                int r = d >> 2, slot = d & 3;
                int j = (slot - (r >> 1)) & 3;
                gld_lds16(Bt + (size_t)r * F + (ks + 1) * BK + j * 8, &Bs[d * 8]);
            }
        }
        #pragma unroll
        for (int mt = 0; mt < 2; mt++)
            #pragma unroll
            for (int nt = 0; nt < 4; nt++)
                acc[mt][nt] = __builtin_amdgcn_mfma_f32_16x16x32_bf16(af[mt], bfr[nt],
                                                                      acc[mt][nt], 0, 0, 0);
        if (ks + 1 < KS) __syncthreads();      // drain DMA -> Bs[ks+1] valid
    }

    if (!FUSE_T) {
        // epilogue: write relu(acc + bias) to C (bf16)
        #pragma unroll
        for (int mt = 0; mt < 2; mt++) {
            #pragma unroll
            for (int nt = 0; nt < 4; nt++) {
                int col = wn * 64 + nt * 16 + mlane;
                float bv = bias[col];
                #pragma unroll
                for (int r = 0; r < 4; r++) {
                    int row = m0 + wm * 32 + mt * 16 + kgrp * 4 + r;
                    if (row < M) {
                        float v = fmaxf(acc[mt][nt][r] + bv, 0.f);
                        C[(size_t)row * BN + col] = f2bf(v);
                    }
                }
            }
        }
    } else {
        // fused layer-3 projection: h2tile = relu(acc + b2) -> Afull (LDS),
        // then t = h2tile @ W3t, stored directly. h2 never reaches HBM.
        __syncthreads();                       // all waves done reading Afull
        #pragma unroll
        for (int mt = 0; mt < 2; mt++) {
            #pragma unroll
            for (int nt = 0; nt < 4; nt++) {
                int col = wn * 64 + nt * 16 + mlane;
                float bv = bias[col];
                #pragma unroll
                for (int r = 0; r < 4; r++) {
                    int rl = wm * 32 + mt * 16 + kgrp * 4 + r;
                    float v = fmaxf(acc[mt][nt][r] + bv, 0.f);
                    Afull[rl * LDAF + col] = f2bf(v);
                }
            }
        }
        __syncthreads();                       // h2 tile ready in LDS
        // t-GEMM: 64x128, K=256. 8 waves: wm2 rows(32), wn2 in 0..3 cols(32).
        int wm2 = wave & 1, wn2 = wave >> 1;
        floatx4 tacc[2][2];
        #pragma unroll
        for (int i = 0; i < 2; i++)
            #pragma unroll
            for (int j = 0; j < 2; j++) tacc[i][j] = (floatx4){0.f, 0.f, 0.f, 0.f};
        for (int ks = 0; ks < 8; ks++) {
            short8 af2[2], bf2r[2];
            #pragma unroll
            for (int nt = 0; nt < 2; nt++)     // W3t from global (64 KB, L2-hot)
                bf2r[nt] = *(const short8*)(W3t + (size_t)(wn2 * 32 + nt * 16 + mlane) * 256
                                            + ks * 32 + kgrp * 8);
            #pragma unroll
            for (int mt = 0; mt < 2; mt++)
                af2[mt] = *(const short8*)&Afull[(wm2 * 32 + mt * 16 + mlane) * LDAF
                                                 + ks * 32 + kgrp * 8];
            #pragma unroll
            for (int mt = 0; mt < 2; mt++)
                #pragma unroll
                for (int nt = 0; nt < 2; nt++)
                    tacc[mt][nt] = __builtin_amdgcn_mfma_f32_16x16x32_bf16(af2[mt], bf2r[nt],
                                                                           tacc[mt][nt], 0, 0, 0);
        }
        #pragma unroll
        for (int mt = 0; mt < 2; mt++) {
            #pragma unroll
            for (int nt = 0; nt < 2; nt++) {
                int col = wn2 * 32 + nt * 16 + mlane;
                #pragma unroll
                for (int r = 0; r < 4; r++) {
                    int row = m0 + wm2 * 32 + mt * 16 + kgrp * 4 + r;
                    if (row < M)
                        tOut[(size_t)row * 128 + col] = f2bf(tacc[mt][nt][r]);
                }
            }
        }
    }
}

// ---------------- Aggregation F=128 body (used by agg3_mean) ------------------------

__device__ inline void agg128_body(const unsigned short* __restrict__ h,
                                   const int* __restrict__ off,
                                   const int* __restrict__ csr,
                                   int node, int quad, int f0, float2* a) {
    int s = __builtin_amdgcn_readfirstlane(off[node]);
    int e = __builtin_amdgcn_readfirstlane(off[node + 1]);
    int i = s;
    for (; i + 8 <= e; i += 8) {
        ushort8v r[2];
        #pragma unroll
        for (int j = 0; j < 2; j++) {
            int base = i + 4 * j;
            int i0 = csr[base], i1 = csr[base + 1], i2 = csr[base + 2], i3 = csr[base + 3];
            int id = quad == 0 ? i0 : quad == 1 ? i1 : quad == 2 ? i2 : i3;
            r[j] = *(const ushort8v*)(h + (size_t)id * 128 + f0);
        }
        #pragma unroll
        for (int j = 0; j < 2; j++) accum16B(a, r[j]);
    }
    int rem = e - i;
    if (rem > 0) {
        int nr = (rem + 3) >> 2;
        ushort8v r[2];
        #pragma unroll
        for (int j = 0; j < 2; j++) {
            if (j < nr) {
                int base = i + 4 * j;
                int c1 = base + 1 < e ? base + 1 : e - 1;
                int c2 = base + 2 < e ? base + 2 : e - 1;
                int c3 = base + 3 < e ? base + 3 : e - 1;
                int i0 = csr[base], i1 = csr[c1], i2 = csr[c2], i3 = csr[c3];
                int id = quad == 0 ? i0 : quad == 1 ? i1 : quad == 2 ? i2 : i3;
                r[j] = *(const ushort8v*)(h + (size_t)id * 128 + f0);
            }
        }
        #pragma unroll
        for (int j = 0; j < 2; j++) {
            if (j < nr && (i + 4 * j + quad) < e) accum16B(a, r[j]);
        }
    }
    #pragma unroll
    for (int p = 0; p < 4; p++) {
        a[p].x += __shfl_xor(a[p].x, 16, 64);
        a[p].y += __shfl_xor(a[p].y, 16, 64);
        a[p].x += __shfl_xor(a[p].x, 32, 64);
        a[p].y += __shfl_xor(a[p].y, 32, 64);
    }
}

// ---------------- layer-3: quad-split agg + bias + relu + block partial mean -------

__global__ __launch_bounds__(256) void agg3_mean_kernel(const unsigned short* __restrict__ t,
                                                        const int* __restrict__ off,
                                                        const int* __restrict__ csr,
                                                        const float* __restrict__ b3,
                                                        float* __restrict__ partial) {
    __shared__ float sm[4 * 128];
    int wave = threadIdx.x >> 6, lane = threadIdx.x & 63;
    int node = blockIdx.x * 4 + wave;
    int quad = lane >> 4;
    int f0 = (lane & 15) * 8;
    float2 a[4];
    #pragma unroll
    for (int p = 0; p < 4; p++) a[p] = make_float2(0.f, 0.f);
    agg128_body(t, off, csr, node, quad, f0, a);
    if (quad == 0) {
        #pragma unroll
        for (int p = 0; p < 4; p++) {
            sm[wave * 128 + f0 + 2 * p]     = fmaxf(a[p].x + b3[f0 + 2 * p], 0.f);
            sm[wave * 128 + f0 + 2 * p + 1] = fmaxf(a[p].y + b3[f0 + 2 * p + 1], 0.f);
        }
    }
    __syncthreads();
    if (threadIdx.x < 128) {
        int f = threadIdx.x;
        float p = sm[f] + sm[128 + f] + sm[256 + f] + sm[384 + f];
        partial[(size_t)blockIdx.x * 128 + f] = p;
    }
}

__global__ __launch_bounds__(256) void mean_reduce_kernel(const float* __restrict__ partial,
                                                          float* __restrict__ outp, int nRows) {
    __shared__ float s[256];
    int f = threadIdx.x & 127, half = threadIdx.x >> 7;
    int chunk = (nRows + gridDim.x - 1) / gridDim.x;
    int r0 = blockIdx.x * chunk;
    int r1 = r0 + chunk < nRows ? r0 + chunk : nRows;
    float acc = 0.f;
    for (int r = r0 + half; r < r1; r += 2) acc += partial[(size_t)r * 128 + f];
    s[threadIdx.x] = acc;
    __syncthreads();
    if (half == 0) atomicAdd(&outp[f], (s[f] + s[f + 128]) * (1.0f / N_NODES));
}

// ---------------- launch ----------------

extern "C" void kernel_launch(void* const* d_in, const int* in_sizes, int n_in,
                              void* d_out, int out_size, void* d_ws, size_t ws_size,
                              hipStream_t stream) {
    const float* x   = (const float*)d_in[0];
    const int*   src = (const int*)d_in[1];
    const int*   dst = (const int*)d_in[2];
    const float* W1 = (const float*)d_in[3];
    const float* b1 = (const float*)d_in[4];
    const float* W2 = (const float*)d_in[5];
    const float* b2 = (const float*)d_in[6];
    const float* W3 = (const float*)d_in[7];
    const float* b3 = (const float*)d_in[8];
    float* out = (float*)d_out;

    char* ws = (char*)d_ws;
    size_t o = 0;
    auto alloc = [&](size_t bytes) -> char* {
        char* p = ws + o;
        o = (o + bytes + 255) & ~(size_t)255;
        return p;
    };
    int* off     = (int*)alloc((size_t)(N_NODES + 1) * 4);
    int* cur     = (int*)alloc((size_t)N_NODES * 4);
    int* csrIdx  = (int*)alloc((size_t)N_EDGES * 4);
    int* bsum    = (int*)alloc(256 * 4);
    unsigned short* Wt1 = (unsigned short*)alloc((size_t)128 * 256 * 2);
    unsigned short* Wt2 = (unsigned short*)alloc((size_t)256 * 256 * 2);
    unsigned short* Wt3 = (unsigned short*)alloc((size_t)256 * 128 * 2);
    char* R1 = alloc((size_t)N_NODES * 256 * 2);
    char* R2 = alloc((size_t)N_NODES * 256 * 2);
    char* R3 = alloc((size_t)N_NODES * 256 * 2);
    (void)alloc(65536);   // guard region

    unsigned short* xb    = (unsigned short*)R1;  // 50000x128 bf16
    unsigned short* h1    = (unsigned short*)R3;  // 50000x256 bf16
    unsigned short* t     = (unsigned short*)R2;  // 50000x128 bf16 (written by fused2)
    float*          pmean = (float*)R1;           // 12500x128 fp32 (xb dead by then)

    const int nb = (N_NODES + 255) / 256;  // 196

    hipMemsetAsync(cur, 0, (size_t)N_NODES * 4, stream);
    const int hpThreads = N_EDGES + 131072 + N_NODES * 128 / 4;
    histprep_kernel<<<(hpThreads + 255) / 256, 256, 0, stream>>>(dst, cur, W1, W2, W3, x,
                                                                 Wt1, Wt2, Wt3, xb, bsum, out);
    scan_onepass_kernel<<<nb, 256, 0, stream>>>(cur, bsum, off, N_NODES);
    fill_kernel<<<(N_EDGES + 255) / 256, 256, 0, stream>>>(src, dst, cur, csrIdx, N_EDGES);

    const int mbF = (N_NODES + 63) / 64;  // 782

    // Layer 1 fused: h1 = relu(agg(xb) @ W1 + b1)
    fused_agg_gemm_kernel<128, false><<<mbF, 512, 0, stream>>>(xb, off, csrIdx, Wt1, b1, h1,
                                                               nullptr, nullptr, N_NODES);
    // Layer 2+3 fused: t = relu(agg(h1) @ W2 + b2) @ W3  (h2 never materialized)
    fused_agg_gemm_kernel<256, true><<<mbF, 512, 0, stream>>>(h1, off, csrIdx, Wt2, b2, nullptr,
                                                              Wt3, t, N_NODES);
    // Layer 3 tail: agg(t) + b3 + relu + partial mean, then reduce
    agg3_mean_kernel<<<N_NODES / 4, 256, 0, stream>>>(t, off, csrIdx, b3, pmean);
    mean_reduce_kernel<<<128, 256, 0, stream>>>(pmean, out, N_NODES / 4);
}